// Round 15
// baseline (399.726 us; speedup 1.0000x reference)
//
#include <hip/hip_runtime.h>
#include <hip/hip_bf16.h>

#define DEVFN __device__ __forceinline__

constexpr int NN = 50000;
constexpr int NE = 800000;
constexpr int NQ = 200000;
constexpr long MP = 50048;   // NN padded to multiple of 128

typedef __attribute__((ext_vector_type(8))) short bf16x8;
typedef __attribute__((ext_vector_type(2))) short s16x2;
typedef __attribute__((ext_vector_type(2))) float f32x2;
typedef __attribute__((ext_vector_type(4))) float f32x4;
typedef __attribute__((address_space(1))) const void gv_t;
typedef __attribute__((address_space(3))) void lv_t;

DEVFN float lrelu(float x) { return x > 0.f ? x : 0.01f * x; }
DEVFN float sigmoidf(float x) { return 1.f / (1.f + __expf(-x)); }
DEVFN float tanh_fast(float x) {
    float xc = fminf(fmaxf(x, -15.f), 15.f);
    float t = __expf(2.f * xc);
    return (t - 1.f) / (t + 1.f);
}

DEVFN short f2b(float v) {
    __hip_bfloat16 h = __float2bfloat16(v);
    return *reinterpret_cast<short*>(&h);
}
DEVFN float b2f(short s) {
    union { unsigned u; float f; } z;
    z.u = ((unsigned)(unsigned short)s) << 16;
    return z.f;
}
DEVFN void gld16(const void* g, void* l) {
    __builtin_amdgcn_global_load_lds((gv_t*)g, (lv_t*)l, 16, 0, 0);
}

#define WAITV3 asm volatile("s_waitcnt vmcnt(3)" ::: "memory")
#define WAITV4 asm volatile("s_waitcnt vmcnt(4)" ::: "memory")
#define WAITV0 asm volatile("s_waitcnt vmcnt(0)" ::: "memory")
#define CFENCE asm volatile("" ::: "memory")

// ---------------------------------------------------------------------------
// Bijective XCD-chunked swizzle (m204): each XCD gets a contiguous work range,
// ordered col-strip-fastest -> A-panel row band stays in that XCD's L2.
// ---------------------------------------------------------------------------
DEVFN void swz_rc(int d, int nwg, int NC, int& rw, int& cs) {
    int q0 = nwg >> 3, rr = nwg & 7;
    int xcd = d & 7, idx = d >> 3;
    int w = (xcd < rr ? xcd * (q0 + 1) : rr * (q0 + 1) + (xcd - rr) * q0) + idx;
    rw = w / NC;
    cs = w - rw * NC;
}

// ---------------------------------------------------------------------------
// GRU interleaved-weight value: W1 [4H][2H]; row n' = g16*64 + chunk*16 + cl;
// real col c = g16*16+cl; chunks: r, z, inn (k<H only), hn (k>=H only).
// ---------------------------------------------------------------------------
template <int H>
DEVFN float gruw_val(const float* Wih, const float* Whh, int i) {
    constexpr int K2 = 2 * H, W3 = 3 * H;
    int np = i / K2, k = i % K2;
    int g16 = np >> 6, chunk = (np >> 4) & 3, cl = np & 15;
    int c = g16 * 16 + cl;
    if (chunk == 0) return (k < H) ? Wih[(long)k * W3 + c] : Whh[(long)(k - H) * W3 + c];
    if (chunk == 1) return (k < H) ? Wih[(long)k * W3 + H + c] : Whh[(long)(k - H) * W3 + H + c];
    if (chunk == 2) return (k < H) ? Wih[(long)k * W3 + 2 * H + c] : 0.f;
    return (k < H) ? 0.f : Whh[(long)(k - H) * W3 + 2 * H + c];
}

// ---------------------------------------------------------------------------
// Mega prep kernel, 8-wide vectorized (one bf16x8 store per unit); degree
// count range stays scalar.
// ---------------------------------------------------------------------------
constexpr long U_XB   = MP * 256 / 8;
constexpr long U_PREV = (long)NN * 256 / 8;
constexpr long U_CNT  = NE;
constexpr long U_P1T  = 65536 / 8;
constexpr long U_P2T  = 32768 / 8;
constexpr long U_C1T  = 32768 / 8;
constexpr long U_C2T  = 32768 / 8;
constexpr long U_W1   = 524288 / 8;
constexpr long U_W2   = 131072 / 8;
constexpr long U_TOT  = U_XB + U_PREV + U_CNT + U_P1T + U_P2T + U_C1T + U_C2T + U_W1 + U_W2;

__global__ void prep_all(const float* __restrict__ x, const float* __restrict__ prev1,
                         const float* __restrict__ pre1W, const float* __restrict__ pre2W,
                         const float* __restrict__ conv1W, const float* __restrict__ conv2W,
                         const float* __restrict__ g1ih, const float* __restrict__ g1hh,
                         const float* __restrict__ g2ih, const float* __restrict__ g2hh,
                         const int* __restrict__ cols, int* __restrict__ cnt,
                         short* __restrict__ xb, short* __restrict__ AP1,
                         short* __restrict__ pre1T, short* __restrict__ pre2T,
                         short* __restrict__ conv1T, short* __restrict__ conv2T,
                         short* __restrict__ W1g1, short* __restrict__ W1g2) {
    long i = (long)blockIdx.x * 256 + threadIdx.x;
    if (i < U_XB) {
        long base = i * 8;
        bf16x8 o;
        if (base < (long)NN * 256) {
            f32x4 a = *(const f32x4*)&x[base];
            f32x4 b = *(const f32x4*)&x[base + 4];
#pragma unroll
            for (int j = 0; j < 4; ++j) { o[j] = f2b(a[j]); o[4 + j] = f2b(b[j]); }
        } else {
            o = bf16x8{0, 0, 0, 0, 0, 0, 0, 0};
        }
        *(bf16x8*)&xb[base] = o;
        return;
    }
    i -= U_XB;
    if (i < U_PREV) {
        long base = i * 8;
        long r = base >> 8;
        int c = (int)(base & 255);
        f32x4 a = *(const f32x4*)&prev1[base];
        f32x4 b = *(const f32x4*)&prev1[base + 4];
        bf16x8 o;
#pragma unroll
        for (int j = 0; j < 4; ++j) { o[j] = f2b(a[j]); o[4 + j] = f2b(b[j]); }
        *(bf16x8*)&AP1[r * 512 + 256 + c] = o;
        return;
    }
    i -= U_PREV;
    if (i < U_CNT) { atomicAdd(&cnt[cols[i]], 1); return; }
    i -= U_CNT;
    if (i < U_P1T) {
        int ii = (int)i * 8, n = ii >> 8, k = ii & 255;
        bf16x8 o;
#pragma unroll
        for (int j = 0; j < 8; ++j) o[j] = f2b(pre1W[(k + j) * 256 + n]);
        *(bf16x8*)&pre1T[ii] = o;
        return;
    }
    i -= U_P1T;
    if (i < U_P2T) {
        int ii = (int)i * 8, n = ii >> 8, k = ii & 255;
        bf16x8 o;
#pragma unroll
        for (int j = 0; j < 8; ++j) o[j] = f2b(pre2W[(k + j) * 128 + n]);
        *(bf16x8*)&pre2T[ii] = o;
        return;
    }
    i -= U_P2T;
    if (i < U_C1T) {
        int ii = (int)i * 8, n = ii >> 7, k = ii & 127;
        bf16x8 o;
#pragma unroll
        for (int j = 0; j < 8; ++j) o[j] = f2b(conv1W[(k + j) * 256 + n]);
        *(bf16x8*)&conv1T[ii] = o;
        return;
    }
    i -= U_C1T;
    if (i < U_C2T) {
        int ii = (int)i * 8, n = ii >> 8, k = ii & 255;
        bf16x8 o;
#pragma unroll
        for (int j = 0; j < 8; ++j) o[j] = f2b(conv2W[(k + j) * 128 + n]);
        *(bf16x8*)&conv2T[ii] = o;
        return;
    }
    i -= U_C2T;
    if (i < U_W1) {
        int ii = (int)i * 8;
        bf16x8 o;
#pragma unroll
        for (int j = 0; j < 8; ++j) o[j] = f2b(gruw_val<256>(g1ih, g1hh, ii + j));
        *(bf16x8*)&W1g1[ii] = o;
        return;
    }
    i -= U_W1;
    if (i < U_W2) {
        int ii = (int)i * 8;
        bf16x8 o;
#pragma unroll
        for (int j = 0; j < 8; ++j) o[j] = f2b(gruw_val<128>(g2ih, g2hh, ii + j));
        *(bf16x8*)&W1g2[ii] = o;
    }
}

// ---------------------------------------------------------------------------
// bf16 MFMA GEMM, 3-buffer counted-vmcnt pipeline + XOR slot swizzle + XCD
// block swizzle + setprio. BM in {64,128}; BN=128; 4 waves.
// ---------------------------------------------------------------------------
template <int EPI, int K, int BM>
__global__ __launch_bounds__(256)
void gemm_mfma(const short* __restrict__ A, const short* __restrict__ Bt,
               const float* __restrict__ bias,
               short* __restrict__ Cb, int obS, int NC, int nwg) {
    constexpr int NS = K / 32;
    constexpr int AQ = BM / 64;
    constexpr int RF = BM / 32;
    __shared__ alignas(16) short As[3][BM * 32];
    __shared__ alignas(16) short Bs[3][4096];
    const int tid = threadIdx.x;
    const int lane = tid & 63, w = tid >> 6;
    const int wr = w >> 1, wc = w & 1;
    int rw, cs;
    swz_rc(blockIdx.x, nwg, NC, rw, cs);
    const long row0 = (long)rw * BM;
    const long col0 = (long)cs * 128;

    f32x4 acc[RF][4] = {};

    const int kcs = ((tid & 3) ^ ((tid >> 3) & 3)) * 8;
    const short* gA = A + (row0 + (tid >> 2)) * (long)K + kcs;
    const short* gB = Bt + (col0 + (tid >> 2)) * (long)K + kcs;
    const long h64 = 64 * (long)K;

    auto stage = [&](int b, int k0) {
#pragma unroll
        for (int q = 0; q < AQ; ++q)
            gld16(gA + q * h64 + k0, &As[b][q * 2048 + tid * 8]);
        gld16(gB + k0, &Bs[b][tid * 8]);
        gld16(gB + h64 + k0, &Bs[b][2048 + tid * 8]);
    };

    stage(0, 0);
    stage(1, 32);
    const int l15 = lane & 15;
    const int kq = ((lane >> 4) ^ ((l15 >> 1) & 3)) * 8;
#pragma unroll
    for (int t = 0; t < NS; ++t) {
        if (t + 1 < NS) {
            if constexpr (AQ == 1) { WAITV3; } else { WAITV4; }
        } else { WAITV0; }
        __builtin_amdgcn_s_barrier();
        CFENCE;
        if (t + 2 < NS) stage((t + 2) % 3, (t + 2) * 32);
        const int cur = t % 3;
        bf16x8 af[RF], bfr[4];
#pragma unroll
        for (int i = 0; i < RF; ++i)
            af[i] = *(const bf16x8*)&As[cur][(wr * (BM / 2) + i * 16 + l15) * 32 + kq];
#pragma unroll
        for (int j = 0; j < 4; ++j)
            bfr[j] = *(const bf16x8*)&Bs[cur][(wc * 64 + j * 16 + l15) * 32 + kq];
        __builtin_amdgcn_s_setprio(1);
#pragma unroll
        for (int i = 0; i < RF; ++i)
#pragma unroll
            for (int j = 0; j < 4; ++j)
                acc[i][j] = __builtin_amdgcn_mfma_f32_16x16x32_bf16(af[i], bfr[j], acc[i][j], 0, 0, 0);
        __builtin_amdgcn_s_setprio(0);
    }

    const int cr = (lane >> 4) * 4, cc = lane & 15;
#pragma unroll
    for (int i = 0; i < RF; ++i) {
#pragma unroll
        for (int j = 0; j < 4; ++j) {
            const long col = col0 + wc * 64 + j * 16 + cc;
            float bv = (EPI == 1) ? bias[col] : 0.f;
#pragma unroll
            for (int r = 0; r < 4; ++r) {
                const long row = row0 + wr * (BM / 2) + i * 16 + cr + r;
                float v = acc[i][j][r];
                if (EPI == 1) v = lrelu(v + bv);
                Cb[row * obS + col] = f2b(v);
            }
        }
    }
}

// ---------------------------------------------------------------------------
// Wide fused GRU, 3-buffer counted-vmcnt pipeline, BM x 128 tile, 4 waves,
// K-split on MFMA/ds_read, XCD block swizzle, setprio. prev read back as
// bf16 from AP's right half. BM in {64,128}.
// ---------------------------------------------------------------------------
template <int H, int BM, bool WRITEB>
__global__ __launch_bounds__(256)
void gru_wide(const short* __restrict__ AP, const short* __restrict__ W1,
              const float* __restrict__ bih, const float* __restrict__ bhh,
              float* __restrict__ outF, short* __restrict__ outB, int M,
              int NC, int nwg) {
    constexpr int K2 = 2 * H;
    constexpr int NS = K2 / 32;
    constexpr int AQ = BM / 64;
    constexpr int RF = BM / 32;
    __shared__ alignas(16) short As[3][BM * 32];
    __shared__ alignas(16) short Bs[3][4096];
    const int tid = threadIdx.x;
    const int lane = tid & 63, w = tid >> 6;
    const int wr = w >> 1, wc = w & 1;
    int rw, cs;
    swz_rc(blockIdx.x, nwg, NC, rw, cs);
    const long row0 = (long)rw * BM;

    f32x4 acc[RF][4] = {};

    const int kcs = ((tid & 3) ^ ((tid >> 3) & 3)) * 8;
    const short* gA = AP + (row0 + (tid >> 2)) * (long)K2 + kcs;
    const short* gB = W1 + ((long)cs * 128 + (tid >> 2)) * (long)K2 + kcs;
    const long h64 = 64 * (long)K2;

    auto stage = [&](int b, int k0) {
#pragma unroll
        for (int q = 0; q < AQ; ++q)
            gld16(gA + q * h64 + k0, &As[b][q * 2048 + tid * 8]);
        gld16(gB + k0, &Bs[b][tid * 8]);
        gld16(gB + h64 + k0, &Bs[b][2048 + tid * 8]);
    };

    stage(0, 0);
    stage(1, 32);
    const int l15 = lane & 15;
    const int kq = ((lane >> 4) ^ ((l15 >> 1) & 3)) * 8;
#pragma unroll
    for (int t = 0; t < NS; ++t) {
        const bool lo = (t * 32 < H);
        if (t + 1 < NS) {
            if constexpr (AQ == 1) { WAITV3; } else { WAITV4; }
        } else { WAITV0; }
        __builtin_amdgcn_s_barrier();
        CFENCE;
        if (t + 2 < NS) stage((t + 2) % 3, (t + 2) * 32);
        const int cur = t % 3;
        bf16x8 af[RF], bfr[4];
#pragma unroll
        for (int i = 0; i < RF; ++i)
            af[i] = *(const bf16x8*)&As[cur][(wr * (BM / 2) + i * 16 + l15) * 32 + kq];
#pragma unroll
        for (int j = 0; j < 4; ++j) {
            if ((j == 2 && !lo) || (j == 3 && lo)) continue;
            bfr[j] = *(const bf16x8*)&Bs[cur][(wc * 64 + j * 16 + l15) * 32 + kq];
        }
        __builtin_amdgcn_s_setprio(1);
#pragma unroll
        for (int i = 0; i < RF; ++i)
#pragma unroll
            for (int j = 0; j < 4; ++j) {
                if ((j == 2 && !lo) || (j == 3 && lo)) continue;
                acc[i][j] = __builtin_amdgcn_mfma_f32_16x16x32_bf16(af[i], bfr[j], acc[i][j], 0, 0, 0);
            }
        __builtin_amdgcn_s_setprio(0);
    }

    // gating epilogue: frag j = chunk j (0=r, 1=z, 2=inn, 3=hn)
    const int cr = (lane >> 4) * 4;
    const int c = cs * 32 + wc * 16 + (lane & 15);
    const float bsr = bih[c] + bhh[c];
    const float bsz = bih[H + c] + bhh[H + c];
    const float bin = bih[2 * H + c];
    const float bhn = bhh[2 * H + c];
#pragma unroll
    for (int i = 0; i < RF; ++i) {
#pragma unroll
        for (int r = 0; r < 4; ++r) {
            const long row = row0 + wr * (BM / 2) + i * 16 + cr + r;
            if (row >= M) continue;
            float rg = sigmoidf(acc[i][0][r] + bsr);
            float zg = sigmoidf(acc[i][1][r] + bsz);
            float ng = tanh_fast(acc[i][2][r] + bin + rg * (acc[i][3][r] + bhn));
            float pv = b2f(AP[row * (long)K2 + H + c]);
            float o = (1.f - zg) * ng + zg * pv;
            outF[row * (long)H + c] = o;
            if (WRITEB) outB[row * (long)H + c] = f2b(o);
        }
    }
}

// ---------------------------------------------------------------------------
// CSR build: scan(+dinv) -> fill  (count lives in prep_all).
// Edge data packed as int2 {src_row, norm_bits}.
// ---------------------------------------------------------------------------
__global__ void scan1(const int* __restrict__ cnt, int* __restrict__ off,
                      int* __restrict__ bsum, float* __restrict__ dinv, int n) {
    __shared__ int sm[256];
    int i = blockIdx.x * 256 + threadIdx.x;
    int v = (i < n) ? cnt[i] : 0;
    if (i < n) dinv[i] = rsqrtf((float)v + 1.0f);   // +1 self-loop
    sm[threadIdx.x] = v;
    __syncthreads();
    for (int s = 1; s < 256; s <<= 1) {
        int t = (threadIdx.x >= s) ? sm[threadIdx.x - s] : 0;
        __syncthreads();
        sm[threadIdx.x] += t;
        __syncthreads();
    }
    if (i < n) off[i + 1] = sm[threadIdx.x];
    if (threadIdx.x == 255) bsum[blockIdx.x] = sm[255];
}

__global__ void scan2(int* __restrict__ bsum, int nb) {
    __shared__ int sm[256];
    int v = (threadIdx.x < nb) ? bsum[threadIdx.x] : 0;
    sm[threadIdx.x] = v;
    __syncthreads();
    for (int s = 1; s < 256; s <<= 1) {
        int t = (threadIdx.x >= s) ? sm[threadIdx.x - s] : 0;
        __syncthreads();
        sm[threadIdx.x] += t;
        __syncthreads();
    }
    if (threadIdx.x < nb) bsum[threadIdx.x] = sm[threadIdx.x] - v;  // exclusive
}

__global__ void scan3(int* __restrict__ off, const int* __restrict__ bsum, int n) {
    int i = blockIdx.x * 256 + threadIdx.x;
    if (i < n) off[i + 1] += bsum[blockIdx.x];
    if (i == 0) off[0] = 0;
}

__global__ void fill_csr(const int* __restrict__ rows, const int* __restrict__ cols,
                         const float* __restrict__ dinv, const int* __restrict__ off,
                         int* __restrict__ cursor, int2* __restrict__ edat, int E) {
    int e = blockIdx.x * 256 + threadIdx.x;
    if (e >= E) return;
    int r = rows[e], c = cols[e];
    int p = off[c] + atomicAdd(&cursor[c], 1);
    int2 d;
    d.x = r;
    d.y = __float_as_int(dinv[r] * dinv[c]);
    edat[p] = d;
}

// ---------------------------------------------------------------------------
// Gather-aggregate over H=128 feats, one wave per dest node, 8x unrolled.
// ---------------------------------------------------------------------------
template <int OS, bool EPI, bool PREV>
__global__ __launch_bounds__(256)
void gather_agg(const short* __restrict__ hwb, const int* __restrict__ off,
                const int2* __restrict__ edat,
                const float* __restrict__ dinv, const float* __restrict__ bias,
                const float* __restrict__ prevf,
                short* __restrict__ aggb, int n) {
    constexpr int H = 128;
    int t = blockIdx.x * 256 + threadIdx.x;
    int c = t >> 6, l = t & 63;
    if (c >= n) return;
    const int fo = l * 2;
    float acc0, acc1;
    {
        float dd = dinv[c] * dinv[c];
        s16x2 v = *(const s16x2*)&hwb[(long)c * H + fo];
        acc0 = b2f(v[0]) * dd;
        acc1 = b2f(v[1]) * dd;
    }
    int e = off[c];
    const int e1 = off[c + 1];
    for (; e + 7 < e1; e += 8) {
        int2 d0 = edat[e], d1 = edat[e + 1], d2 = edat[e + 2], d3 = edat[e + 3];
        int2 d4 = edat[e + 4], d5 = edat[e + 5], d6 = edat[e + 6], d7 = edat[e + 7];
        s16x2 v0 = *(const s16x2*)&hwb[(long)d0.x * H + fo];
        s16x2 v1 = *(const s16x2*)&hwb[(long)d1.x * H + fo];
        s16x2 v2 = *(const s16x2*)&hwb[(long)d2.x * H + fo];
        s16x2 v3 = *(const s16x2*)&hwb[(long)d3.x * H + fo];
        s16x2 v4 = *(const s16x2*)&hwb[(long)d4.x * H + fo];
        s16x2 v5 = *(const s16x2*)&hwb[(long)d5.x * H + fo];
        s16x2 v6 = *(const s16x2*)&hwb[(long)d6.x * H + fo];
        s16x2 v7 = *(const s16x2*)&hwb[(long)d7.x * H + fo];
        float n0 = __int_as_float(d0.y), n1 = __int_as_float(d1.y);
        float n2 = __int_as_float(d2.y), n3 = __int_as_float(d3.y);
        float n4 = __int_as_float(d4.y), n5 = __int_as_float(d5.y);
        float n6 = __int_as_float(d6.y), n7 = __int_as_float(d7.y);
        acc0 += b2f(v0[0]) * n0 + b2f(v1[0]) * n1 + b2f(v2[0]) * n2 + b2f(v3[0]) * n3
              + b2f(v4[0]) * n4 + b2f(v5[0]) * n5 + b2f(v6[0]) * n6 + b2f(v7[0]) * n7;
        acc1 += b2f(v0[1]) * n0 + b2f(v1[1]) * n1 + b2f(v2[1]) * n2 + b2f(v3[1]) * n3
              + b2f(v4[1]) * n4 + b2f(v5[1]) * n5 + b2f(v6[1]) * n6 + b2f(v7[1]) * n7;
    }
    for (; e < e1; ++e) {
        int2 d0 = edat[e];
        float n0 = __int_as_float(d0.y);
        s16x2 v0 = *(const s16x2*)&hwb[(long)d0.x * H + fo];
        acc0 += b2f(v0[0]) * n0;
        acc1 += b2f(v0[1]) * n0;
    }
    s16x2 o;
    if (EPI) {
        o[0] = f2b(lrelu(acc0 + bias[fo]));
        o[1] = f2b(lrelu(acc1 + bias[fo + 1]));
    } else {
        o[0] = f2b(acc0);
        o[1] = f2b(acc1);
    }
    *(s16x2*)&aggb[(long)c * OS + fo] = o;
    if (PREV) {
        f32x2 p = *(const f32x2*)&prevf[(long)c * H + fo];
        s16x2 pb;
        pb[0] = f2b(p[0]);
        pb[1] = f2b(p[1]);
        *(s16x2*)&aggb[(long)c * OS + H + fo] = pb;
    }
}

// ---------------------------------------------------------------------------
// Per-node partial dots: u[n] = emb2[n] . pw[0:128], v[n] = emb2[n] . pw[128:256]
// ---------------------------------------------------------------------------
__global__ void node_dots(const short* __restrict__ emb2b, const float* __restrict__ pw,
                          float* __restrict__ u, float* __restrict__ v, int n) {
    int t = blockIdx.x * 256 + threadIdx.x;
    int c = t >> 6, l = t & 63;
    if (c >= n) return;
    const int f = l * 2;
    s16x2 e = *(const s16x2*)&emb2b[(long)c * 128 + f];
    float e0 = b2f(e[0]), e1 = b2f(e[1]);
    float ua = e0 * pw[f] + e1 * pw[f + 1];
    float va = e0 * pw[128 + f] + e1 * pw[128 + f + 1];
#pragma unroll
    for (int off = 32; off > 0; off >>= 1) {
        ua += __shfl_down(ua, off);
        va += __shfl_down(va, off);
    }
    if (l == 0) { u[c] = ua; v[c] = va; }
}

// ---------------------------------------------------------------------------
// Edge scores: 16 lanes per edge; ea-dot + gathered u[s] + v[d]
// ---------------------------------------------------------------------------
__global__ void edge_lite(const int* __restrict__ eli, const float* __restrict__ ea,
                          const float* __restrict__ pw, const float* __restrict__ pb,
                          const float* __restrict__ u, const float* __restrict__ v,
                          float* __restrict__ scores, int Q) {
    int t = blockIdx.x * 256 + threadIdx.x;
    int e = t >> 4, l = t & 15;
    if (e >= Q) return;
    float acc = ea[(long)e * 16 + l] * pw[256 + l];
#pragma unroll
    for (int off = 8; off > 0; off >>= 1) acc += __shfl_down(acc, off, 16);
    if (l == 0) {
        int s = eli[e], d = eli[Q + e];
        scores[e] = acc + u[s] + v[d] + pb[0];
    }
}

// ---------------------------------------------------------------------------

extern "C" void kernel_launch(void* const* d_in, const int* in_sizes, int n_in,
                              void* d_out, int out_size, void* d_ws, size_t ws_size,
                              hipStream_t stream) {
    const float* x       = (const float*)d_in[0];
    const int*   ei      = (const int*)d_in[1];
    const int*   eli     = (const int*)d_in[2];
    const float* eattr   = (const float*)d_in[3];
    const float* prev1   = (const float*)d_in[4];
    const float* prev2   = (const float*)d_in[5];
    const float* pre1_W  = (const float*)d_in[6];
    const float* pre1_b  = (const float*)d_in[7];
    const float* pre2_W  = (const float*)d_in[8];
    const float* pre2_b  = (const float*)d_in[9];
    const float* conv1_W = (const float*)d_in[10];
    const float* conv1_b = (const float*)d_in[11];
    const float* conv2_W = (const float*)d_in[12];
    const float* conv2_b = (const float*)d_in[13];
    const float* g1_Wih  = (const float*)d_in[14];
    const float* g1_Whh  = (const float*)d_in[15];
    const float* g1_bih  = (const float*)d_in[16];
    const float* g1_bhh  = (const float*)d_in[17];
    const float* g2_Wih  = (const float*)d_in[18];
    const float* g2_Whh  = (const float*)d_in[19];
    const float* g2_bih  = (const float*)d_in[20];
    const float* g2_bhh  = (const float*)d_in[21];
    const float* post_W  = (const float*)d_in[22];
    const float* post_b  = (const float*)d_in[23];

    float* out    = (float*)d_out;
    float* scores = out;                      // [NQ]
    float* emb1   = out + NQ;                 // [N,256]
    float* emb2   = emb1 + (long)NN * 256;    // [N,128]

    // workspace layout (bytes)
    char* ws = (char*)d_ws;
    const long S256 = MP * 256 * 2;           // 25,624,576
    const long S128 = MP * 128 * 2;           // 12,812,288
    short* R1  = (short*)ws;                          // xb -> G1 -> AP2
    short* R2  = (short*)(ws + S256);                 // h1b -> emb1b
    short* R3  = (short*)(ws + 2 * S256);             // h2b -> hw2b -> emb2b
    short* AP1 = (short*)(ws + 2 * S256 + S128);      // [MP][512]
    short* AP2 = R1;                                  // [MP][256], aliases R1
    char*  wts = ws + 4 * S256 + S128;
    short* pre1T  = (short*)wts;            // [256][256]
    short* pre2T  = pre1T + 256 * 256;      // [128][256]
    short* conv1T = pre2T + 128 * 256;      // [256][128]
    short* conv2T = conv1T + 256 * 128;     // [128][256]
    short* W1g1   = conv2T + 128 * 256;     // [1024][512]
    short* W1g2   = W1g1 + 1024 * 512;      // [512][256]
    float* dinv   = (float*)(W1g2 + 512 * 256);   // [NN]
    int*   cnt    = (int*)(dinv + NN);            // [NN]
    int*   cursor = cnt + NN;                     // [NN]
    int2*  edat   = (int2*)(cursor + NN);         // [NE] 8B-aligned
    int*   off    = (int*)(edat + NE);            // [NN+1]
    int*   bsum   = off + NN + 1;                 // [256]
    float* uvec   = (float*)(bsum + 256);         // [NN]
    float* vvec   = uvec + NN;                    // [NN]

    const int* rows = ei;
    const int* cols = ei + NE;

    dim3 blk(256);
    const int NB = (NN + 255) / 256;   // 196

    // --- memset cnt+cursor, then mega prep (vectorized conversions + count) ---
    hipMemsetAsync(cnt, 0, 2 * NN * sizeof(int), stream);
    prep_all<<<(int)((U_TOT + 255) / 256), blk, 0, stream>>>(
        x, prev1, pre1_W, pre2_W, conv1_W, conv2_W,
        g1_Wih, g1_Whh, g2_Wih, g2_Whh, cols, cnt,
        R1, AP1, pre1T, pre2T, conv1T, conv2T, W1g1, W1g2);

    // --- CSR build (once, reused by both layers) ---
    scan1<<<NB, blk, 0, stream>>>(cnt, off, bsum, dinv, NN);
    scan2<<<1, blk, 0, stream>>>(bsum, NB);
    scan3<<<NB, blk, 0, stream>>>(off, bsum, NN);
    fill_csr<<<(NE + 255) / 256, blk, 0, stream>>>(rows, cols, dinv, off, cursor, edat, NE);

    // --- dense pre-layers (BM=64: more resident blocks for latency regime) ---
    gemm_mfma<1, 256, 64><<<1564, blk, 0, stream>>>(R1, pre1T, pre1_b, R2, 256, 2, 1564);
    gemm_mfma<1, 256, 64><<<782, blk, 0, stream>>>(R2, pre2T, pre2_b, R3, 128, 1, 782);

    // --- GCN1: aggregate on 128-dim h2 (raw), then conv1 GEMM -> AP1 left ---
    gather_agg<128, false, false><<<(NN + 3) / 4, blk, 0, stream>>>(
        R3, off, edat, dinv, nullptr, nullptr, R1, NN);
    gemm_mfma<1, 128, 64><<<1564, blk, 0, stream>>>(R1, conv1T, conv1_b, AP1, 512, 2, 1564);

    // --- GRU1 (BM=64: max TLP for latency-slack regime) -> emb1 + emb1b (R2) ---
    gru_wide<256, 64, true><<<6256, blk, 0, stream>>>(AP1, W1g1, g1_bih, g1_bhh,
                                                      emb1, R2, NN, 8, 6256);

    // --- conv2 ---
    gemm_mfma<0, 256, 64><<<782, blk, 0, stream>>>(R2, conv2T, nullptr, R3, 128, 1, 782);

    // --- GCN2: aggregate (fused bias+lrelu) + prev2 copy -> AP2 ---
    gather_agg<256, true, true><<<(NN + 3) / 4, blk, 0, stream>>>(
        R3, off, edat, dinv, conv2_b, prev2, AP2, NN);

    // --- GRU2 (BM=64) -> emb2 + emb2b (R3) ---
    gru_wide<128, 64, true><<<3128, blk, 0, stream>>>(AP2, W1g2, g2_bih, g2_bhh,
                                                      emb2, R3, NN, 4, 3128);

    // --- edge scores: per-node dots then slim edge kernel ---
    node_dots<<<(NN + 3) / 4, blk, 0, stream>>>(R3, post_W, uvec, vvec, NN);
    edge_lite<<<(NQ + 15) / 16, blk, 0, stream>>>(eli, eattr, post_W, post_b,
                                                  uvec, vvec, scores, NQ);
}

// Round 16
// 386.853 us; speedup vs baseline: 1.0333x; 1.0333x over previous
//
#include <hip/hip_runtime.h>
#include <hip/hip_bf16.h>

#define DEVFN __device__ __forceinline__

constexpr int NN = 50000;
constexpr int NE = 800000;
constexpr int NQ = 200000;
constexpr long MP = 50048;   // NN padded to multiple of 128

typedef __attribute__((ext_vector_type(8))) short bf16x8;
typedef __attribute__((ext_vector_type(2))) short s16x2;
typedef __attribute__((ext_vector_type(2))) float f32x2;
typedef __attribute__((ext_vector_type(4))) float f32x4;
typedef __attribute__((address_space(1))) const void gv_t;
typedef __attribute__((address_space(3))) void lv_t;

DEVFN float lrelu(float x) { return x > 0.f ? x : 0.01f * x; }
DEVFN float sigmoidf(float x) { return 1.f / (1.f + __expf(-x)); }
DEVFN float tanh_fast(float x) {
    float xc = fminf(fmaxf(x, -15.f), 15.f);
    float t = __expf(2.f * xc);
    return (t - 1.f) / (t + 1.f);
}

DEVFN short f2b(float v) {
    __hip_bfloat16 h = __float2bfloat16(v);
    return *reinterpret_cast<short*>(&h);
}
DEVFN float b2f(short s) {
    union { unsigned u; float f; } z;
    z.u = ((unsigned)(unsigned short)s) << 16;
    return z.f;
}
DEVFN void gld16(const void* g, void* l) {
    __builtin_amdgcn_global_load_lds((gv_t*)g, (lv_t*)l, 16, 0, 0);
}

#define WAITV3 asm volatile("s_waitcnt vmcnt(3)" ::: "memory")
#define WAITV4 asm volatile("s_waitcnt vmcnt(4)" ::: "memory")
#define WAITV0 asm volatile("s_waitcnt vmcnt(0)" ::: "memory")
#define CFENCE asm volatile("" ::: "memory")

// ---------------------------------------------------------------------------
// Bijective XCD-chunked swizzle (m204): each XCD gets a contiguous work range,
// ordered col-strip-fastest -> A-panel row band stays in that XCD's L2.
// ---------------------------------------------------------------------------
DEVFN void swz_rc(int d, int nwg, int NC, int& rw, int& cs) {
    int q0 = nwg >> 3, rr = nwg & 7;
    int xcd = d & 7, idx = d >> 3;
    int w = (xcd < rr ? xcd * (q0 + 1) : rr * (q0 + 1) + (xcd - rr) * q0) + idx;
    rw = w / NC;
    cs = w - rw * NC;
}

// ---------------------------------------------------------------------------
// GRU interleaved-weight value: W1 [4H][2H]; row n' = g16*64 + chunk*16 + cl;
// real col c = g16*16+cl; chunks: r, z, inn (k<H only), hn (k>=H only).
// ---------------------------------------------------------------------------
template <int H>
DEVFN float gruw_val(const float* Wih, const float* Whh, int i) {
    constexpr int K2 = 2 * H, W3 = 3 * H;
    int np = i / K2, k = i % K2;
    int g16 = np >> 6, chunk = (np >> 4) & 3, cl = np & 15;
    int c = g16 * 16 + cl;
    if (chunk == 0) return (k < H) ? Wih[(long)k * W3 + c] : Whh[(long)(k - H) * W3 + c];
    if (chunk == 1) return (k < H) ? Wih[(long)k * W3 + H + c] : Whh[(long)(k - H) * W3 + H + c];
    if (chunk == 2) return (k < H) ? Wih[(long)k * W3 + 2 * H + c] : 0.f;
    return (k < H) ? 0.f : Whh[(long)(k - H) * W3 + 2 * H + c];
}

// ---------------------------------------------------------------------------
// Mega prep kernel, 8-wide vectorized (one bf16x8 store per unit); degree
// count range stays scalar.
// ---------------------------------------------------------------------------
constexpr long U_XB   = MP * 256 / 8;
constexpr long U_PREV = (long)NN * 256 / 8;
constexpr long U_CNT  = NE;
constexpr long U_P1T  = 65536 / 8;
constexpr long U_P2T  = 32768 / 8;
constexpr long U_C1T  = 32768 / 8;
constexpr long U_C2T  = 32768 / 8;
constexpr long U_W1   = 524288 / 8;
constexpr long U_W2   = 131072 / 8;
constexpr long U_TOT  = U_XB + U_PREV + U_CNT + U_P1T + U_P2T + U_C1T + U_C2T + U_W1 + U_W2;

__global__ void prep_all(const float* __restrict__ x, const float* __restrict__ prev1,
                         const float* __restrict__ pre1W, const float* __restrict__ pre2W,
                         const float* __restrict__ conv1W, const float* __restrict__ conv2W,
                         const float* __restrict__ g1ih, const float* __restrict__ g1hh,
                         const float* __restrict__ g2ih, const float* __restrict__ g2hh,
                         const int* __restrict__ cols, int* __restrict__ cnt,
                         short* __restrict__ xb, short* __restrict__ AP1,
                         short* __restrict__ pre1T, short* __restrict__ pre2T,
                         short* __restrict__ conv1T, short* __restrict__ conv2T,
                         short* __restrict__ W1g1, short* __restrict__ W1g2) {
    long i = (long)blockIdx.x * 256 + threadIdx.x;
    if (i < U_XB) {
        long base = i * 8;
        bf16x8 o;
        if (base < (long)NN * 256) {
            f32x4 a = *(const f32x4*)&x[base];
            f32x4 b = *(const f32x4*)&x[base + 4];
#pragma unroll
            for (int j = 0; j < 4; ++j) { o[j] = f2b(a[j]); o[4 + j] = f2b(b[j]); }
        } else {
            o = bf16x8{0, 0, 0, 0, 0, 0, 0, 0};
        }
        *(bf16x8*)&xb[base] = o;
        return;
    }
    i -= U_XB;
    if (i < U_PREV) {
        long base = i * 8;
        long r = base >> 8;
        int c = (int)(base & 255);
        f32x4 a = *(const f32x4*)&prev1[base];
        f32x4 b = *(const f32x4*)&prev1[base + 4];
        bf16x8 o;
#pragma unroll
        for (int j = 0; j < 4; ++j) { o[j] = f2b(a[j]); o[4 + j] = f2b(b[j]); }
        *(bf16x8*)&AP1[r * 512 + 256 + c] = o;
        return;
    }
    i -= U_PREV;
    if (i < U_CNT) { atomicAdd(&cnt[cols[i]], 1); return; }
    i -= U_CNT;
    if (i < U_P1T) {
        int ii = (int)i * 8, n = ii >> 8, k = ii & 255;
        bf16x8 o;
#pragma unroll
        for (int j = 0; j < 8; ++j) o[j] = f2b(pre1W[(k + j) * 256 + n]);
        *(bf16x8*)&pre1T[ii] = o;
        return;
    }
    i -= U_P1T;
    if (i < U_P2T) {
        int ii = (int)i * 8, n = ii >> 8, k = ii & 255;
        bf16x8 o;
#pragma unroll
        for (int j = 0; j < 8; ++j) o[j] = f2b(pre2W[(k + j) * 128 + n]);
        *(bf16x8*)&pre2T[ii] = o;
        return;
    }
    i -= U_P2T;
    if (i < U_C1T) {
        int ii = (int)i * 8, n = ii >> 7, k = ii & 127;
        bf16x8 o;
#pragma unroll
        for (int j = 0; j < 8; ++j) o[j] = f2b(conv1W[(k + j) * 256 + n]);
        *(bf16x8*)&conv1T[ii] = o;
        return;
    }
    i -= U_C1T;
    if (i < U_C2T) {
        int ii = (int)i * 8, n = ii >> 8, k = ii & 255;
        bf16x8 o;
#pragma unroll
        for (int j = 0; j < 8; ++j) o[j] = f2b(conv2W[(k + j) * 128 + n]);
        *(bf16x8*)&conv2T[ii] = o;
        return;
    }
    i -= U_C2T;
    if (i < U_W1) {
        int ii = (int)i * 8;
        bf16x8 o;
#pragma unroll
        for (int j = 0; j < 8; ++j) o[j] = f2b(gruw_val<256>(g1ih, g1hh, ii + j));
        *(bf16x8*)&W1g1[ii] = o;
        return;
    }
    i -= U_W1;
    if (i < U_W2) {
        int ii = (int)i * 8;
        bf16x8 o;
#pragma unroll
        for (int j = 0; j < 8; ++j) o[j] = f2b(gruw_val<128>(g2ih, g2hh, ii + j));
        *(bf16x8*)&W1g2[ii] = o;
    }
}

// ---------------------------------------------------------------------------
// bf16 MFMA GEMM, 3-buffer counted-vmcnt pipeline + XOR slot swizzle + XCD
// block swizzle + setprio. BM in {64,128}; BN=128; 4 waves.
// ---------------------------------------------------------------------------
template <int EPI, int K, int BM>
__global__ __launch_bounds__(256)
void gemm_mfma(const short* __restrict__ A, const short* __restrict__ Bt,
               const float* __restrict__ bias,
               short* __restrict__ Cb, int obS, int NC, int nwg) {
    constexpr int NS = K / 32;
    constexpr int AQ = BM / 64;
    constexpr int RF = BM / 32;
    __shared__ alignas(16) short As[3][BM * 32];
    __shared__ alignas(16) short Bs[3][4096];
    const int tid = threadIdx.x;
    const int lane = tid & 63, w = tid >> 6;
    const int wr = w >> 1, wc = w & 1;
    int rw, cs;
    swz_rc(blockIdx.x, nwg, NC, rw, cs);
    const long row0 = (long)rw * BM;
    const long col0 = (long)cs * 128;

    f32x4 acc[RF][4] = {};

    const int kcs = ((tid & 3) ^ ((tid >> 3) & 3)) * 8;
    const short* gA = A + (row0 + (tid >> 2)) * (long)K + kcs;
    const short* gB = Bt + (col0 + (tid >> 2)) * (long)K + kcs;
    const long h64 = 64 * (long)K;

    auto stage = [&](int b, int k0) {
#pragma unroll
        for (int q = 0; q < AQ; ++q)
            gld16(gA + q * h64 + k0, &As[b][q * 2048 + tid * 8]);
        gld16(gB + k0, &Bs[b][tid * 8]);
        gld16(gB + h64 + k0, &Bs[b][2048 + tid * 8]);
    };

    stage(0, 0);
    stage(1, 32);
    const int l15 = lane & 15;
    const int kq = ((lane >> 4) ^ ((l15 >> 1) & 3)) * 8;
#pragma unroll
    for (int t = 0; t < NS; ++t) {
        if (t + 1 < NS) {
            if constexpr (AQ == 1) { WAITV3; } else { WAITV4; }
        } else { WAITV0; }
        __builtin_amdgcn_s_barrier();
        CFENCE;
        if (t + 2 < NS) stage((t + 2) % 3, (t + 2) * 32);
        const int cur = t % 3;
        bf16x8 af[RF], bfr[4];
#pragma unroll
        for (int i = 0; i < RF; ++i)
            af[i] = *(const bf16x8*)&As[cur][(wr * (BM / 2) + i * 16 + l15) * 32 + kq];
#pragma unroll
        for (int j = 0; j < 4; ++j)
            bfr[j] = *(const bf16x8*)&Bs[cur][(wc * 64 + j * 16 + l15) * 32 + kq];
        __builtin_amdgcn_s_setprio(1);
#pragma unroll
        for (int i = 0; i < RF; ++i)
#pragma unroll
            for (int j = 0; j < 4; ++j)
                acc[i][j] = __builtin_amdgcn_mfma_f32_16x16x32_bf16(af[i], bfr[j], acc[i][j], 0, 0, 0);
        __builtin_amdgcn_s_setprio(0);
    }

    const int cr = (lane >> 4) * 4, cc = lane & 15;
#pragma unroll
    for (int i = 0; i < RF; ++i) {
#pragma unroll
        for (int j = 0; j < 4; ++j) {
            const long col = col0 + wc * 64 + j * 16 + cc;
            float bv = (EPI == 1) ? bias[col] : 0.f;
#pragma unroll
            for (int r = 0; r < 4; ++r) {
                const long row = row0 + wr * (BM / 2) + i * 16 + cr + r;
                float v = acc[i][j][r];
                if (EPI == 1) v = lrelu(v + bv);
                Cb[row * obS + col] = f2b(v);
            }
        }
    }
}

// ---------------------------------------------------------------------------
// Wide fused GRU, 3-buffer counted-vmcnt pipeline, BM x 128 tile, 4 waves,
// K-split on MFMA/ds_read, XCD block swizzle, setprio. prev read back as
// bf16 from AP's right half. BM in {64,128}.
// ---------------------------------------------------------------------------
template <int H, int BM, bool WRITEB>
__global__ __launch_bounds__(256)
void gru_wide(const short* __restrict__ AP, const short* __restrict__ W1,
              const float* __restrict__ bih, const float* __restrict__ bhh,
              float* __restrict__ outF, short* __restrict__ outB, int M,
              int NC, int nwg) {
    constexpr int K2 = 2 * H;
    constexpr int NS = K2 / 32;
    constexpr int AQ = BM / 64;
    constexpr int RF = BM / 32;
    __shared__ alignas(16) short As[3][BM * 32];
    __shared__ alignas(16) short Bs[3][4096];
    const int tid = threadIdx.x;
    const int lane = tid & 63, w = tid >> 6;
    const int wr = w >> 1, wc = w & 1;
    int rw, cs;
    swz_rc(blockIdx.x, nwg, NC, rw, cs);
    const long row0 = (long)rw * BM;

    f32x4 acc[RF][4] = {};

    const int kcs = ((tid & 3) ^ ((tid >> 3) & 3)) * 8;
    const short* gA = AP + (row0 + (tid >> 2)) * (long)K2 + kcs;
    const short* gB = W1 + ((long)cs * 128 + (tid >> 2)) * (long)K2 + kcs;
    const long h64 = 64 * (long)K2;

    auto stage = [&](int b, int k0) {
#pragma unroll
        for (int q = 0; q < AQ; ++q)
            gld16(gA + q * h64 + k0, &As[b][q * 2048 + tid * 8]);
        gld16(gB + k0, &Bs[b][tid * 8]);
        gld16(gB + h64 + k0, &Bs[b][2048 + tid * 8]);
    };

    stage(0, 0);
    stage(1, 32);
    const int l15 = lane & 15;
    const int kq = ((lane >> 4) ^ ((l15 >> 1) & 3)) * 8;
#pragma unroll
    for (int t = 0; t < NS; ++t) {
        const bool lo = (t * 32 < H);
        if (t + 1 < NS) {
            if constexpr (AQ == 1) { WAITV3; } else { WAITV4; }
        } else { WAITV0; }
        __builtin_amdgcn_s_barrier();
        CFENCE;
        if (t + 2 < NS) stage((t + 2) % 3, (t + 2) * 32);
        const int cur = t % 3;
        bf16x8 af[RF], bfr[4];
#pragma unroll
        for (int i = 0; i < RF; ++i)
            af[i] = *(const bf16x8*)&As[cur][(wr * (BM / 2) + i * 16 + l15) * 32 + kq];
#pragma unroll
        for (int j = 0; j < 4; ++j) {
            if ((j == 2 && !lo) || (j == 3 && lo)) continue;
            bfr[j] = *(const bf16x8*)&Bs[cur][(wc * 64 + j * 16 + l15) * 32 + kq];
        }
        __builtin_amdgcn_s_setprio(1);
#pragma unroll
        for (int i = 0; i < RF; ++i)
#pragma unroll
            for (int j = 0; j < 4; ++j) {
                if ((j == 2 && !lo) || (j == 3 && lo)) continue;
                acc[i][j] = __builtin_amdgcn_mfma_f32_16x16x32_bf16(af[i], bfr[j], acc[i][j], 0, 0, 0);
            }
        __builtin_amdgcn_s_setprio(0);
    }

    // gating epilogue: frag j = chunk j (0=r, 1=z, 2=inn, 3=hn)
    const int cr = (lane >> 4) * 4;
    const int c = cs * 32 + wc * 16 + (lane & 15);
    const float bsr = bih[c] + bhh[c];
    const float bsz = bih[H + c] + bhh[H + c];
    const float bin = bih[2 * H + c];
    const float bhn = bhh[2 * H + c];
#pragma unroll
    for (int i = 0; i < RF; ++i) {
#pragma unroll
        for (int r = 0; r < 4; ++r) {
            const long row = row0 + wr * (BM / 2) + i * 16 + cr + r;
            if (row >= M) continue;
            float rg = sigmoidf(acc[i][0][r] + bsr);
            float zg = sigmoidf(acc[i][1][r] + bsz);
            float ng = tanh_fast(acc[i][2][r] + bin + rg * (acc[i][3][r] + bhn));
            float pv = b2f(AP[row * (long)K2 + H + c]);
            float o = (1.f - zg) * ng + zg * pv;
            outF[row * (long)H + c] = o;
            if (WRITEB) outB[row * (long)H + c] = f2b(o);
        }
    }
}

// ---------------------------------------------------------------------------
// CSR build: scan(+dinv) -> fill  (count lives in prep_all).
// Edge data packed as int2 {src_row, norm_bits}.
// ---------------------------------------------------------------------------
__global__ void scan1(const int* __restrict__ cnt, int* __restrict__ off,
                      int* __restrict__ bsum, float* __restrict__ dinv, int n) {
    __shared__ int sm[256];
    int i = blockIdx.x * 256 + threadIdx.x;
    int v = (i < n) ? cnt[i] : 0;
    if (i < n) dinv[i] = rsqrtf((float)v + 1.0f);   // +1 self-loop
    sm[threadIdx.x] = v;
    __syncthreads();
    for (int s = 1; s < 256; s <<= 1) {
        int t = (threadIdx.x >= s) ? sm[threadIdx.x - s] : 0;
        __syncthreads();
        sm[threadIdx.x] += t;
        __syncthreads();
    }
    if (i < n) off[i + 1] = sm[threadIdx.x];
    if (threadIdx.x == 255) bsum[blockIdx.x] = sm[255];
}

__global__ void scan2(int* __restrict__ bsum, int nb) {
    __shared__ int sm[256];
    int v = (threadIdx.x < nb) ? bsum[threadIdx.x] : 0;
    sm[threadIdx.x] = v;
    __syncthreads();
    for (int s = 1; s < 256; s <<= 1) {
        int t = (threadIdx.x >= s) ? sm[threadIdx.x - s] : 0;
        __syncthreads();
        sm[threadIdx.x] += t;
        __syncthreads();
    }
    if (threadIdx.x < nb) bsum[threadIdx.x] = sm[threadIdx.x] - v;  // exclusive
}

__global__ void scan3(int* __restrict__ off, const int* __restrict__ bsum, int n) {
    int i = blockIdx.x * 256 + threadIdx.x;
    if (i < n) off[i + 1] += bsum[blockIdx.x];
    if (i == 0) off[0] = 0;
}

__global__ void fill_csr(const int* __restrict__ rows, const int* __restrict__ cols,
                         const float* __restrict__ dinv, const int* __restrict__ off,
                         int* __restrict__ cursor, int2* __restrict__ edat, int E) {
    int e = blockIdx.x * 256 + threadIdx.x;
    if (e >= E) return;
    int r = rows[e], c = cols[e];
    int p = off[c] + atomicAdd(&cursor[c], 1);
    int2 d;
    d.x = r;
    d.y = __float_as_int(dinv[r] * dinv[c]);
    edat[p] = d;
}

// ---------------------------------------------------------------------------
// Gather-aggregate over H=128 feats, one wave per dest node, 8x unrolled.
// ---------------------------------------------------------------------------
template <int OS, bool EPI, bool PREV>
__global__ __launch_bounds__(256)
void gather_agg(const short* __restrict__ hwb, const int* __restrict__ off,
                const int2* __restrict__ edat,
                const float* __restrict__ dinv, const float* __restrict__ bias,
                const float* __restrict__ prevf,
                short* __restrict__ aggb, int n) {
    constexpr int H = 128;
    int t = blockIdx.x * 256 + threadIdx.x;
    int c = t >> 6, l = t & 63;
    if (c >= n) return;
    const int fo = l * 2;
    float acc0, acc1;
    {
        float dd = dinv[c] * dinv[c];
        s16x2 v = *(const s16x2*)&hwb[(long)c * H + fo];
        acc0 = b2f(v[0]) * dd;
        acc1 = b2f(v[1]) * dd;
    }
    int e = off[c];
    const int e1 = off[c + 1];
    for (; e + 7 < e1; e += 8) {
        int2 d0 = edat[e], d1 = edat[e + 1], d2 = edat[e + 2], d3 = edat[e + 3];
        int2 d4 = edat[e + 4], d5 = edat[e + 5], d6 = edat[e + 6], d7 = edat[e + 7];
        s16x2 v0 = *(const s16x2*)&hwb[(long)d0.x * H + fo];
        s16x2 v1 = *(const s16x2*)&hwb[(long)d1.x * H + fo];
        s16x2 v2 = *(const s16x2*)&hwb[(long)d2.x * H + fo];
        s16x2 v3 = *(const s16x2*)&hwb[(long)d3.x * H + fo];
        s16x2 v4 = *(const s16x2*)&hwb[(long)d4.x * H + fo];
        s16x2 v5 = *(const s16x2*)&hwb[(long)d5.x * H + fo];
        s16x2 v6 = *(const s16x2*)&hwb[(long)d6.x * H + fo];
        s16x2 v7 = *(const s16x2*)&hwb[(long)d7.x * H + fo];
        float n0 = __int_as_float(d0.y), n1 = __int_as_float(d1.y);
        float n2 = __int_as_float(d2.y), n3 = __int_as_float(d3.y);
        float n4 = __int_as_float(d4.y), n5 = __int_as_float(d5.y);
        float n6 = __int_as_float(d6.y), n7 = __int_as_float(d7.y);
        acc0 += b2f(v0[0]) * n0 + b2f(v1[0]) * n1 + b2f(v2[0]) * n2 + b2f(v3[0]) * n3
              + b2f(v4[0]) * n4 + b2f(v5[0]) * n5 + b2f(v6[0]) * n6 + b2f(v7[0]) * n7;
        acc1 += b2f(v0[1]) * n0 + b2f(v1[1]) * n1 + b2f(v2[1]) * n2 + b2f(v3[1]) * n3
              + b2f(v4[1]) * n4 + b2f(v5[1]) * n5 + b2f(v6[1]) * n6 + b2f(v7[1]) * n7;
    }
    for (; e < e1; ++e) {
        int2 d0 = edat[e];
        float n0 = __int_as_float(d0.y);
        s16x2 v0 = *(const s16x2*)&hwb[(long)d0.x * H + fo];
        acc0 += b2f(v0[0]) * n0;
        acc1 += b2f(v0[1]) * n0;
    }
    s16x2 o;
    if (EPI) {
        o[0] = f2b(lrelu(acc0 + bias[fo]));
        o[1] = f2b(lrelu(acc1 + bias[fo + 1]));
    } else {
        o[0] = f2b(acc0);
        o[1] = f2b(acc1);
    }
    *(s16x2*)&aggb[(long)c * OS + fo] = o;
    if (PREV) {
        f32x2 p = *(const f32x2*)&prevf[(long)c * H + fo];
        s16x2 pb;
        pb[0] = f2b(p[0]);
        pb[1] = f2b(p[1]);
        *(s16x2*)&aggb[(long)c * OS + H + fo] = pb;
    }
}

// ---------------------------------------------------------------------------
// Per-node partial dots: u[n] = emb2[n] . pw[0:128], v[n] = emb2[n] . pw[128:256]
// ---------------------------------------------------------------------------
__global__ void node_dots(const short* __restrict__ emb2b, const float* __restrict__ pw,
                          float* __restrict__ u, float* __restrict__ v, int n) {
    int t = blockIdx.x * 256 + threadIdx.x;
    int c = t >> 6, l = t & 63;
    if (c >= n) return;
    const int f = l * 2;
    s16x2 e = *(const s16x2*)&emb2b[(long)c * 128 + f];
    float e0 = b2f(e[0]), e1 = b2f(e[1]);
    float ua = e0 * pw[f] + e1 * pw[f + 1];
    float va = e0 * pw[128 + f] + e1 * pw[128 + f + 1];
#pragma unroll
    for (int off = 32; off > 0; off >>= 1) {
        ua += __shfl_down(ua, off);
        va += __shfl_down(va, off);
    }
    if (l == 0) { u[c] = ua; v[c] = va; }
}

// ---------------------------------------------------------------------------
// Edge scores: 16 lanes per edge; ea-dot + gathered u[s] + v[d]
// ---------------------------------------------------------------------------
__global__ void edge_lite(const int* __restrict__ eli, const float* __restrict__ ea,
                          const float* __restrict__ pw, const float* __restrict__ pb,
                          const float* __restrict__ u, const float* __restrict__ v,
                          float* __restrict__ scores, int Q) {
    int t = blockIdx.x * 256 + threadIdx.x;
    int e = t >> 4, l = t & 15;
    if (e >= Q) return;
    float acc = ea[(long)e * 16 + l] * pw[256 + l];
#pragma unroll
    for (int off = 8; off > 0; off >>= 1) acc += __shfl_down(acc, off, 16);
    if (l == 0) {
        int s = eli[e], d = eli[Q + e];
        scores[e] = acc + u[s] + v[d] + pb[0];
    }
}

// ---------------------------------------------------------------------------

extern "C" void kernel_launch(void* const* d_in, const int* in_sizes, int n_in,
                              void* d_out, int out_size, void* d_ws, size_t ws_size,
                              hipStream_t stream) {
    const float* x       = (const float*)d_in[0];
    const int*   ei      = (const int*)d_in[1];
    const int*   eli     = (const int*)d_in[2];
    const float* eattr   = (const float*)d_in[3];
    const float* prev1   = (const float*)d_in[4];
    const float* prev2   = (const float*)d_in[5];
    const float* pre1_W  = (const float*)d_in[6];
    const float* pre1_b  = (const float*)d_in[7];
    const float* pre2_W  = (const float*)d_in[8];
    const float* pre2_b  = (const float*)d_in[9];
    const float* conv1_W = (const float*)d_in[10];
    const float* conv1_b = (const float*)d_in[11];
    const float* conv2_W = (const float*)d_in[12];
    const float* conv2_b = (const float*)d_in[13];
    const float* g1_Wih  = (const float*)d_in[14];
    const float* g1_Whh  = (const float*)d_in[15];
    const float* g1_bih  = (const float*)d_in[16];
    const float* g1_bhh  = (const float*)d_in[17];
    const float* g2_Wih  = (const float*)d_in[18];
    const float* g2_Whh  = (const float*)d_in[19];
    const float* g2_bih  = (const float*)d_in[20];
    const float* g2_bhh  = (const float*)d_in[21];
    const float* post_W  = (const float*)d_in[22];
    const float* post_b  = (const float*)d_in[23];

    float* out    = (float*)d_out;
    float* scores = out;                      // [NQ]
    float* emb1   = out + NQ;                 // [N,256]
    float* emb2   = emb1 + (long)NN * 256;    // [N,128]

    // workspace layout (bytes)
    char* ws = (char*)d_ws;
    const long S256 = MP * 256 * 2;           // 25,624,576
    const long S128 = MP * 128 * 2;           // 12,812,288
    short* R1  = (short*)ws;                          // xb -> G1 -> AP2
    short* R2  = (short*)(ws + S256);                 // h1b -> emb1b
    short* R3  = (short*)(ws + 2 * S256);             // h2b -> hw2b -> emb2b
    short* AP1 = (short*)(ws + 2 * S256 + S128);      // [MP][512]
    short* AP2 = R1;                                  // [MP][256], aliases R1
    char*  wts = ws + 4 * S256 + S128;
    short* pre1T  = (short*)wts;            // [256][256]
    short* pre2T  = pre1T + 256 * 256;      // [128][256]
    short* conv1T = pre2T + 128 * 256;      // [256][128]
    short* conv2T = conv1T + 256 * 128;     // [128][256]
    short* W1g1   = conv2T + 128 * 256;     // [1024][512]
    short* W1g2   = W1g1 + 1024 * 512;      // [512][256]
    float* dinv   = (float*)(W1g2 + 512 * 256);   // [NN]
    int*   cnt    = (int*)(dinv + NN);            // [NN]
    int*   cursor = cnt + NN;                     // [NN]
    int2*  edat   = (int2*)(cursor + NN);         // [NE] 8B-aligned
    int*   off    = (int*)(edat + NE);            // [NN+1]
    int*   bsum   = off + NN + 1;                 // [256]
    float* uvec   = (float*)(bsum + 256);         // [NN]
    float* vvec   = uvec + NN;                    // [NN]

    const int* rows = ei;
    const int* cols = ei + NE;

    dim3 blk(256);
    const int NB = (NN + 255) / 256;   // 196

    // --- memset cnt+cursor, then mega prep (vectorized conversions + count) ---
    hipMemsetAsync(cnt, 0, 2 * NN * sizeof(int), stream);
    prep_all<<<(int)((U_TOT + 255) / 256), blk, 0, stream>>>(
        x, prev1, pre1_W, pre2_W, conv1_W, conv2_W,
        g1_Wih, g1_Whh, g2_Wih, g2_Whh, cols, cnt,
        R1, AP1, pre1T, pre2T, conv1T, conv2T, W1g1, W1g2);

    // --- CSR build (once, reused by both layers) ---
    scan1<<<NB, blk, 0, stream>>>(cnt, off, bsum, dinv, NN);
    scan2<<<1, blk, 0, stream>>>(bsum, NB);
    scan3<<<NB, blk, 0, stream>>>(off, bsum, NN);
    fill_csr<<<(NE + 255) / 256, blk, 0, stream>>>(rows, cols, dinv, off, cursor, edat, NE);

    // --- dense pre-layers (BM=64: more resident blocks for latency regime) ---
    gemm_mfma<1, 256, 64><<<1564, blk, 0, stream>>>(R1, pre1T, pre1_b, R2, 256, 2, 1564);
    gemm_mfma<1, 256, 64><<<782, blk, 0, stream>>>(R2, pre2T, pre2_b, R3, 128, 1, 782);

    // --- GCN1: aggregate on 128-dim h2 (raw), then conv1 GEMM -> AP1 left ---
    gather_agg<128, false, false><<<(NN + 3) / 4, blk, 0, stream>>>(
        R3, off, edat, dinv, nullptr, nullptr, R1, NN);
    gemm_mfma<1, 128, 64><<<1564, blk, 0, stream>>>(R1, conv1T, conv1_b, AP1, 512, 2, 1564);

    // --- GRU1 (BM=128, empirical optimum) -> emb1 fp32 + emb1b (R2) ---
    gru_wide<256, 128, true><<<3128, blk, 0, stream>>>(AP1, W1g1, g1_bih, g1_bhh,
                                                       emb1, R2, NN, 8, 3128);

    // --- conv2 ---
    gemm_mfma<0, 256, 64><<<782, blk, 0, stream>>>(R2, conv2T, nullptr, R3, 128, 1, 782);

    // --- GCN2: aggregate (fused bias+lrelu) + prev2 copy -> AP2 ---
    gather_agg<256, true, true><<<(NN + 3) / 4, blk, 0, stream>>>(
        R3, off, edat, dinv, conv2_b, prev2, AP2, NN);

    // --- GRU2 (BM=64) -> emb2 + emb2b (R3) ---
    gru_wide<128, 64, true><<<3128, blk, 0, stream>>>(AP2, W1g2, g2_bih, g2_bhh,
                                                      emb2, R3, NN, 4, 3128);

    // --- edge scores: per-node dots then slim edge kernel ---
    node_dots<<<(NN + 3) / 4, blk, 0, stream>>>(R3, post_W, uvec, vvec, NN);
    edge_lite<<<(NQ + 15) / 16, blk, 0, stream>>>(eli, eattr, post_W, post_b,
                                                  uvec, vvec, scores, NQ);
}